// Round 1
// 246.891 us; speedup vs baseline: 1.1158x; 1.1158x over previous
//
#include <hip/hip_runtime.h>
#include <hip/hip_bf16.h>
#include <cstdint>
#include <cstddef>

typedef __attribute__((ext_vector_type(8))) short short8;
typedef __attribute__((ext_vector_type(4))) short short4v;
typedef __attribute__((ext_vector_type(4))) float floatx4;
typedef unsigned short ushort_t;

#define LOG2E 1.44269504088896340736f

__device__ __forceinline__ unsigned short f2bf(float f) {
    unsigned u = __float_as_uint(f);
    u += 0x7FFFu + ((u >> 16) & 1u);   // RNE
    return (unsigned short)(u >> 16);
}
__device__ __forceinline__ float bf2f(unsigned short s) {
    return __uint_as_float(((unsigned)s) << 16);
}

// ---------------------------------------------------------------------------
// wprep: W fp32 (256x256) -> bf16 once.
// ---------------------------------------------------------------------------
__global__ __launch_bounds__(256) void wprep(const float* __restrict__ W,
                                             ushort_t* __restrict__ Wb) {
    int t = blockIdx.x * 256 + threadIdx.x;   // 16384 float4s
    float4 v = ((const float4*)W)[t];
    short4v s;
    s[0] = (short)f2bf(v.x); s[1] = (short)f2bf(v.y);
    s[2] = (short)f2bf(v.z); s[3] = (short)f2bf(v.w);
    ((short4v*)Wb)[t] = s;
}

// ---------------------------------------------------------------------------
// gemm_h: hT[b][o][j] = sum_k x[b][j][k]*W[o][k]  (bf16 out, o-major).
// Block = 64 j-rows x ALL 256 o  ->  x fp32 read exactly once from HBM.
// W staged in LDS in four 32KB K-quarters (LDS <= 36 KB).
// Epilogue: hT store + full s_src/s_dst (no atomics, written once).
// ---------------------------------------------------------------------------
__global__ __launch_bounds__(256) void gemm_h(const float* __restrict__ x,
                                              const ushort_t* __restrict__ Wb,
                                              ushort_t* __restrict__ hT,
                                              const float* __restrict__ a_src,
                                              const float* __restrict__ a_dst,
                                              float* __restrict__ s_src,
                                              float* __restrict__ s_dst) {
    const int tid = threadIdx.x;
    const int w = tid >> 6, lane = tid & 63;
    const int q = lane >> 4, t16 = lane & 15;

    __shared__ ushort_t wt[256][72];   // 256 o-rows x 64 k (quarter), +8 pad

    // load this wave's 16 x-rows (fp32 -> bf16 A-frags, all K upfront)
    const int jrow = blockIdx.x * 64 + w * 16 + t16;
    const float* xr = x + (size_t)jrow * 256 + q * 8;
    short8 af[8];
#pragma unroll
    for (int kb = 0; kb < 8; ++kb) {
        float4 v0 = *(const float4*)(xr + kb * 32);
        float4 v1 = *(const float4*)(xr + kb * 32 + 4);
        short8 a;
        a[0] = (short)f2bf(v0.x); a[1] = (short)f2bf(v0.y);
        a[2] = (short)f2bf(v0.z); a[3] = (short)f2bf(v0.w);
        a[4] = (short)f2bf(v1.x); a[5] = (short)f2bf(v1.y);
        a[6] = (short)f2bf(v1.z); a[7] = (short)f2bf(v1.w);
        af[kb] = a;
    }

    floatx4 acc[16] = {};
#pragma unroll
    for (int kp = 0; kp < 4; ++kp) {
        if (kp) __syncthreads();       // protect wt overwrite
        // stage W K-quarter: 2048 int4s, 8 per thread
#pragma unroll
        for (int r = 0; r < 8; ++r) {
            int G = tid + 256 * r;
            int row = G >> 3, g = G & 7;
            int4 wv = *(const int4*)(Wb + (size_t)row * 256 + kp * 64 + g * 8);
            *(int4*)(&wt[row][g * 8]) = wv;
        }
        __syncthreads();
#pragma unroll
        for (int ks = 0; ks < 2; ++ks) {
#pragma unroll
            for (int ct = 0; ct < 16; ++ct) {
                short8 bf = *(const short8*)(&wt[ct * 16 + t16][ks * 32 + q * 8]);
                acc[ct] = __builtin_amdgcn_mfma_f32_16x16x32_bf16(af[kp * 2 + ks], bf, acc[ct], 0, 0, 0);
            }
        }
    }

    // hT store: D col=t16 -> o_local, row=q*4+r -> j_local
    const int jbase = blockIdx.x * 64 + w * 16 + q * 4;   // flat b*2048+j
    const int b = jbase >> 11, jj = jbase & 2047;
#pragma unroll
    for (int ct = 0; ct < 16; ++ct) {
        const int o = ct * 16 + t16;
        short4v sv;
        sv[0] = (short)f2bf(acc[ct][0]);
        sv[1] = (short)f2bf(acc[ct][1]);
        sv[2] = (short)f2bf(acc[ct][2]);
        sv[3] = (short)f2bf(acc[ct][3]);
        *(short4v*)(hT + ((size_t)b * 256 + o) * 2048 + jj) = sv;
    }

    // s_src/s_dst: full dot over o (16 cts in-lane, then 16-lane shuffle)
    float psv[4] = {}, pdv[4] = {};
#pragma unroll
    for (int ct = 0; ct < 16; ++ct) {
        const int o = ct * 16 + t16;
        float as = a_src[o], ad = a_dst[o];
#pragma unroll
        for (int r = 0; r < 4; ++r) {
            psv[r] = __fmaf_rn(acc[ct][r], as, psv[r]);
            pdv[r] = __fmaf_rn(acc[ct][r], ad, pdv[r]);
        }
    }
#pragma unroll
    for (int m = 1; m < 16; m <<= 1) {
#pragma unroll
        for (int r = 0; r < 4; ++r) {
            psv[r] += __shfl_xor(psv[r], m);
            pdv[r] += __shfl_xor(pdv[r], m);
        }
    }
    if (t16 == 0) {
#pragma unroll
        for (int r = 0; r < 4; ++r) {
            s_src[jbase + r] = psv[r];
            s_dst[jbase + r] = pdv[r];
        }
    }
}

// ---------------------------------------------------------------------------
// attn: O[i][o] = (1/l_i) sum_j p[i][j] * hT[o][j],
// p = exp2(lrelu(si+sd)*log2e) masked by adj (read directly, streamed).
// Block = 64 i x 256 o, grid (b=8, iblk=32) -> same-b blocks share XCD L2
// for the 1MB hT slice (linear id = b + 8*iblk -> XCD = b).
//
// v2: 1024 threads (16 waves = 4 waves/SIMD). Previous 256-thread version
// gave 1 wave/SIMD (Occupancy 9.3%, MfmaUtil 5.9%) -- pure latency-bound.
// Same chunk pipeline: 64 chunks of 32 j, adj+hT prefetched into regs one
// chunk ahead, hT tile + p tile double-buffered in LDS, 1 barrier/chunk.
// Work split: hT stage = 1 int4/thread; p-produce = 2 elems/thread
// (prow = tid&63, j-pair = wave idx); consume: wave w -> 16i x 64o tile
// (osub = (w&3)*64, ih = (w>>2)*16), 4 MFMA/chunk.
// LDS ~62 KB (static <64 KB); acc[4] -> low VGPR, fits 4 waves/SIMD.
// ---------------------------------------------------------------------------
__global__ __launch_bounds__(1024) void attn(const ushort_t* __restrict__ hT,
                                             const int* __restrict__ adj,
                                             const float* __restrict__ s_src,
                                             const float* __restrict__ s_dst,
                                             float* __restrict__ out) {
    const int tid = threadIdx.x;           // 0..1023
    const int w = tid >> 6;                // wave 0..15
    const int lane = tid & 63;
    const int q = lane >> 4, t16 = lane & 15;
    const int b = blockIdx.x;
    const int i0 = blockIdx.y * 64;

    __shared__ ushort_t hts[2][256][40];   // 256 o x 32 j (+8 pad) : 40 KB
    __shared__ ushort_t ps[2][64][40];     // 64 i x 32 j (+8 pad)  : 10 KB
    __shared__ float sdl[2048];            // s_dst * log2e          : 8 KB
    __shared__ float lred[64][16];         // per-wave lsum partials : 4 KB
    __shared__ float rll[64];

    // stage s_dst*log2e (2 floats/thread)
    const float* sdb = s_dst + (size_t)b * 2048;
    {
        int idx = tid * 2;
        float2 v = *(const float2*)(sdb + idx);
        v.x *= LOG2E; v.y *= LOG2E;
        *(float2*)(&sdl[idx]) = v;
    }

    // p-producer mapping: row = tid&63, j-pair index = wave idx (j = w*2+{0,1})
    const int prow = lane;
    const float si = s_src[(size_t)b * 2048 + i0 + prow] * LOG2E;
    const int* adjr = adj + ((size_t)b * 2048 + i0 + prow) * 2048 + w * 2;

    // hT stage mapping: row = tid>>2, 8-j segment = tid&3 (16 B/thread)
    const int hrow = tid >> 2, hseg = tid & 3;
    const ushort_t* hTg = hT + ((size_t)b * 256 + hrow) * 2048 + hseg * 8;

    // consumer mapping: wave tile 16 i x 64 o
    const int osub = (w & 3) * 64, ih = (w >> 2) * 16;

    floatx4 acc[4] = {};
    float lsum = 0.f;
    int4 hreg;
    int2 a2;

    // prologue: prefetch chunk 0
    hreg = *(const int4*)(hTg);
    a2 = *(const int2*)(adjr);
    __syncthreads();   // sdl ready

    for (int c = 0; c < 64; ++c) {
        const int buf = c & 1;
        // stage hT chunk from regs
        *(int4*)(&hts[buf][hrow][hseg * 8]) = hreg;
        // produce p tile (2 elems/thread)
        {
            float2 sd = *(const float2*)(&sdl[c * 32 + w * 2]);
            float t0 = si + sd.x;
            float t1 = si + sd.y;
            float l0 = fmaxf(t0, 0.2f * t0);
            float l1 = fmaxf(t1, 0.2f * t1);
            float p0 = __builtin_amdgcn_exp2f(l0);
            float p1 = __builtin_amdgcn_exp2f(l1);
            p0 = (a2.x != 0) ? p0 : 0.0f;
            p1 = (a2.y != 0) ? p1 : 0.0f;
            unsigned short u0 = f2bf(p0);
            unsigned short u1 = f2bf(p1);
            lsum += bf2f(u0) + bf2f(u1);
            unsigned pw = (unsigned)u0 | ((unsigned)u1 << 16);
            *(unsigned*)(&ps[buf][prow][w * 2]) = pw;
        }
        // prefetch chunk c+1 (regs; latency hidden across barrier)
        if (c < 63) {
            hreg = *(const int4*)(hTg + (c + 1) * 32);
            a2 = *(const int2*)(adjr + (size_t)(c + 1) * 32);
        }
        __syncthreads();
        // consume: K=32 (one kstep), wave tile 16i x 64o
        short8 bf = *(const short8*)(&ps[buf][ih + t16][q * 8]);
#pragma unroll
        for (int ct = 0; ct < 4; ++ct) {
            short8 af = *(const short8*)(&hts[buf][osub + ct * 16 + t16][q * 8]);
            acc[ct] = __builtin_amdgcn_mfma_f32_16x16x32_bf16(af, bf, acc[ct], 0, 0, 0);
        }
    }

    // row sums -> 1/l
    lred[prow][w] = lsum;
    __syncthreads();
    if (tid < 64) {
        float s = 0.f;
#pragma unroll
        for (int k = 0; k < 16; ++k) s += lred[tid][k];
        rll[tid] = (s > 0.f) ? 1.0f / s : 0.0f;
    }
    __syncthreads();

    // epilogue: D col=t16 -> i_local, row=q*4+r -> o_local
    {
        const int i = ih + t16;
        const float rl = rll[i];
        float* orow = out + ((size_t)b * 2048 + i0 + i) * 256 + osub + q * 4;
#pragma unroll
        for (int ct = 0; ct < 4; ++ct) {
            floatx4 v = acc[ct] * rl;
            *(floatx4*)(orow + ct * 16) = v;
        }
    }
}

extern "C" void kernel_launch(void* const* d_in, const int* in_sizes, int n_in,
                              void* d_out, int out_size, void* d_ws, size_t ws_size,
                              hipStream_t stream) {
    const float* x     = (const float*)d_in[0];
    const int*   adj   = (const int*)d_in[1];
    const float* W     = (const float*)d_in[2];
    const float* a_src = (const float*)d_in[3];
    const float* a_dst = (const float*)d_in[4];
    float* out = (float*)d_out;

    // 8.25 MB total scratch (round-2-proven footprint)
    char* ws = (char*)d_ws;
    ushort_t* hT = (ushort_t*)ws;                                   // [0, 8M)
    float* s_src = (float*)(ws + (size_t)8 * 1024 * 1024);          // 64 KB
    float* s_dst = s_src + 16384;                                   // 64 KB
    ushort_t* Wb = (ushort_t*)(s_dst + 16384);                      // 128 KB

    wprep<<<64, 256, 0, stream>>>(W, Wb);
    gemm_h<<<256, 256, 0, stream>>>(x, Wb, hT, a_src, a_dst, s_src, s_dst);
    attn<<<dim3(8, 32), 1024, 0, stream>>>(hT, adj, s_src, s_dst, out);
}